// Round 4
// baseline (1587.205 us; speedup 1.0000x reference)
//
#include <hip/hip_runtime.h>
#include <hip/hip_bf16.h>

// GCN 2-layer: h1' = relu(S·(x@w1) + b1); out = S·(h1'@w2) + b2
// Bucket sort edges into 782 buckets of 128 dst-nodes (coalesced 4-kernel
// multisplit, no contended atomics), then aggregate per bucket with an LDS
// fp32 accumulator (edge-parallel, ds-atomic adds, fused bias/relu).
// Intermediates bf16. N=100000, E=1600000, IN=128, HID=64, OUT=64.

#define N_NODES 100000
#define N_EDGES 1600000
#define NBUCK   782     // ceil(N/128): bucket = 128 consecutive dst nodes
#define TILE    2048
#define NBLK_E  782     // ceil(E/TILE)

typedef unsigned short ushort_t;
typedef unsigned int uint_t;

static __device__ __forceinline__ float bf2f(ushort_t h) {
    return __uint_as_float(((uint_t)h) << 16);
}
static __device__ __forceinline__ ushort_t f2bf(float f) {
    uint_t u = __float_as_uint(f);
    u = (u + 0x7FFF + ((u >> 16) & 1)) >> 16;   // RNE
    return (ushort_t)u;
}

// ---------------------------------------------------------------------------
// Bucket sort stage 1: per-tile bucket histogram (LDS), write counts row.
// ---------------------------------------------------------------------------
__global__ __launch_bounds__(256) void k_count(
    const int* __restrict__ dst, int* __restrict__ counts, int E)
{
    __shared__ int cnt[NBUCK];
    const int tid = threadIdx.x;
    for (int i = tid; i < NBUCK; i += 256) cnt[i] = 0;
    __syncthreads();
    const int e0 = blockIdx.x * TILE;
    const int e1 = min(E, e0 + TILE);
    for (int e = e0 + tid; e < e1; e += 256)
        atomicAdd(&cnt[dst[e] >> 7], 1);
    __syncthreads();
    int* row = counts + (size_t)blockIdx.x * NBUCK;
    for (int i = tid; i < NBUCK; i += 256) row[i] = cnt[i];
}

// ---------------------------------------------------------------------------
// Stage 2: per-bucket exclusive scan over tiles (column of counts matrix).
// ---------------------------------------------------------------------------
__global__ __launch_bounds__(1024) void k_colscan(
    const int* __restrict__ counts, int* __restrict__ offs,
    int* __restrict__ total)
{
    __shared__ int s[1024];
    const int t = threadIdx.x, k = blockIdx.x;
    const int v = (t < NBLK_E) ? counts[(size_t)t * NBUCK + k] : 0;
    s[t] = v;
    #pragma unroll
    for (int off = 1; off < 1024; off <<= 1) {
        __syncthreads();
        int a = (t >= off) ? s[t - off] : 0;
        __syncthreads();
        s[t] += a;
    }
    __syncthreads();
    if (t < NBLK_E) offs[(size_t)t * NBUCK + k] = s[t] - v;
    if (t == NBLK_E - 1) total[k] = s[t];
}

// Stage 3: exclusive scan of bucket totals -> bucket bases.
__global__ __launch_bounds__(1024) void k_totscan(
    const int* __restrict__ total, int* __restrict__ base)
{
    __shared__ int s[1024];
    const int t = threadIdx.x;
    const int v = (t < NBUCK) ? total[t] : 0;
    s[t] = v;
    #pragma unroll
    for (int off = 1; off < 1024; off <<= 1) {
        __syncthreads();
        int a = (t >= off) ? s[t - off] : 0;
        __syncthreads();
        s[t] += a;
    }
    __syncthreads();
    if (t < NBUCK) base[t] = s[t] - v;
}

// ---------------------------------------------------------------------------
// Stage 4: LDS multisplit placement. Re-bin tile in LDS, stream out grouped
// by bucket (coalesced runs). rec.x = (dst&127)<<17 | src, rec.y = fp32 w.
// ---------------------------------------------------------------------------
__global__ __launch_bounds__(1024) void k_placeB(
    const int* __restrict__ src, const int* __restrict__ dst,
    const float* __restrict__ ew, const int* __restrict__ offs,
    const int* __restrict__ base, int2* __restrict__ recs, int E)
{
    __shared__ int cnt[NBUCK];
    __shared__ int start[NBUCK];
    __shared__ int cursor[NBUCK];
    __shared__ int gbase[NBUCK];
    __shared__ int s[1024];
    __shared__ int2 stg[TILE];
    __shared__ ushort_t sb[TILE];
    const int t = threadIdx.x, b = blockIdx.x;

    for (int i = t; i < NBUCK; i += 1024) cnt[i] = 0;
    __syncthreads();
    const int e0 = b * TILE;
    const int e1 = min(E, e0 + TILE);
    for (int e = e0 + t; e < e1; e += 1024)
        atomicAdd(&cnt[dst[e] >> 7], 1);
    __syncthreads();
    const int v = (t < NBUCK) ? cnt[t] : 0;
    s[t] = v;
    #pragma unroll
    for (int off = 1; off < 1024; off <<= 1) {
        __syncthreads();
        int a = (t >= off) ? s[t - off] : 0;
        __syncthreads();
        s[t] += a;
    }
    __syncthreads();
    if (t < NBUCK) {
        int st = s[t] - v;
        start[t]  = st;
        cursor[t] = st;
        gbase[t]  = base[t] + offs[(size_t)b * NBUCK + t];
    }
    __syncthreads();
    for (int e = e0 + t; e < e1; e += 1024) {
        int d  = dst[e];
        int bk = d >> 7;
        int p  = atomicAdd(&cursor[bk], 1);
        int2 r;
        r.x = ((d & 127) << 17) | src[e];
        r.y = __float_as_int(ew[e]);
        stg[p] = r;
        sb[p]  = (ushort_t)bk;
    }
    __syncthreads();
    const int n = e1 - e0;
    for (int i = t; i < n; i += 1024) {
        int bk = sb[i];
        recs[gbase[bk] + (i - start[bk])] = stg[i];
    }
}

// ---------------------------------------------------------------------------
// GEMM1: Y[bf16, N x 64] = X[f32, N x 128] @ W[128 x 64]
// 64 rows x 64 cols / 256-thread block; thread = 4 rows x 4 cols.
// ---------------------------------------------------------------------------
__global__ __launch_bounds__(256) void k_gemm1(
    const float* __restrict__ X, const float* __restrict__ W,
    ushort_t* __restrict__ Y, int N)
{
    const int K = 128;
    __shared__ float sW[K * 64];
    __shared__ float sX[64 * (K + 4)];
    const int tid  = threadIdx.x;
    const int row0 = blockIdx.x * 64;

    #pragma unroll
    for (int i = tid * 4; i < K * 64; i += 256 * 4)
        *(float4*)(sW + i) = *(const float4*)(W + i);
    #pragma unroll
    for (int i = tid; i < 64 * (K / 4); i += 256) {
        int r  = i >> 5;
        int c4 = (i & 31) * 4;
        int rg = row0 + r; if (rg > N - 1) rg = N - 1;
        *(float4*)(sX + r * (K + 4) + c4) =
            *(const float4*)(X + (size_t)rg * K + c4);
    }
    __syncthreads();

    const int c0 = (tid & 15) * 4;
    const int r0 = (tid >> 4) * 4;
    float acc[4][4];
    #pragma unroll
    for (int i = 0; i < 4; ++i)
        #pragma unroll
        for (int j = 0; j < 4; ++j) acc[i][j] = 0.f;

    for (int k4 = 0; k4 < K; k4 += 4) {
        float4 xv[4];
        #pragma unroll
        for (int i = 0; i < 4; ++i)
            xv[i] = *(const float4*)(sX + (r0 + i) * (K + 4) + k4);
        #pragma unroll
        for (int kk = 0; kk < 4; ++kk) {
            float4 wv = *(const float4*)(sW + (k4 + kk) * 64 + c0);
            #pragma unroll
            for (int i = 0; i < 4; ++i) {
                float xs = (kk == 0) ? xv[i].x : (kk == 1) ? xv[i].y
                         : (kk == 2) ? xv[i].z : xv[i].w;
                acc[i][0] = fmaf(xs, wv.x, acc[i][0]);
                acc[i][1] = fmaf(xs, wv.y, acc[i][1]);
                acc[i][2] = fmaf(xs, wv.z, acc[i][2]);
                acc[i][3] = fmaf(xs, wv.w, acc[i][3]);
            }
        }
    }
    #pragma unroll
    for (int i = 0; i < 4; ++i) {
        int rg = row0 + r0 + i;
        if (rg < N) {
            ushort4 pk = make_ushort4(f2bf(acc[i][0]), f2bf(acc[i][1]),
                                      f2bf(acc[i][2]), f2bf(acc[i][3]));
            *(ushort4*)(Y + (size_t)rg * 64 + c0) = pk;
        }
    }
}

// ---------------------------------------------------------------------------
// GEMM2: Y[bf16, N x 64] = X[bf16, N x 64] @ W[64 x 64]
// ---------------------------------------------------------------------------
__global__ __launch_bounds__(256) void k_gemm2(
    const ushort_t* __restrict__ X, const float* __restrict__ W,
    ushort_t* __restrict__ Y, int N)
{
    const int K = 64;
    __shared__ float sW[K * 64];
    __shared__ float sX[64 * (K + 4)];
    const int tid  = threadIdx.x;
    const int row0 = blockIdx.x * 64;

    #pragma unroll
    for (int i = tid * 4; i < K * 64; i += 256 * 4)
        *(float4*)(sW + i) = *(const float4*)(W + i);
    #pragma unroll
    for (int i = tid; i < 64 * (K / 4); i += 256) {
        int r  = i >> 4;
        int c4 = (i & 15) * 4;
        int rg = row0 + r; if (rg > N - 1) rg = N - 1;
        ushort4 v = *(const ushort4*)(X + (size_t)rg * K + c4);
        float* o = sX + r * (K + 4) + c4;
        o[0] = bf2f(v.x); o[1] = bf2f(v.y); o[2] = bf2f(v.z); o[3] = bf2f(v.w);
    }
    __syncthreads();

    const int c0 = (tid & 15) * 4;
    const int r0 = (tid >> 4) * 4;
    float acc[4][4];
    #pragma unroll
    for (int i = 0; i < 4; ++i)
        #pragma unroll
        for (int j = 0; j < 4; ++j) acc[i][j] = 0.f;

    for (int k4 = 0; k4 < K; k4 += 4) {
        float4 xv[4];
        #pragma unroll
        for (int i = 0; i < 4; ++i)
            xv[i] = *(const float4*)(sX + (r0 + i) * (K + 4) + k4);
        #pragma unroll
        for (int kk = 0; kk < 4; ++kk) {
            float4 wv = *(const float4*)(sW + (k4 + kk) * 64 + c0);
            #pragma unroll
            for (int i = 0; i < 4; ++i) {
                float xs = (kk == 0) ? xv[i].x : (kk == 1) ? xv[i].y
                         : (kk == 2) ? xv[i].z : xv[i].w;
                acc[i][0] = fmaf(xs, wv.x, acc[i][0]);
                acc[i][1] = fmaf(xs, wv.y, acc[i][1]);
                acc[i][2] = fmaf(xs, wv.z, acc[i][2]);
                acc[i][3] = fmaf(xs, wv.w, acc[i][3]);
            }
        }
    }
    #pragma unroll
    for (int i = 0; i < 4; ++i) {
        int rg = row0 + r0 + i;
        if (rg < N) {
            ushort4 pk = make_ushort4(f2bf(acc[i][0]), f2bf(acc[i][1]),
                                      f2bf(acc[i][2]), f2bf(acc[i][3]));
            *(ushort4*)(Y + (size_t)rg * 64 + c0) = pk;
        }
    }
}

// ---------------------------------------------------------------------------
// Aggregate one bucket (128 dst nodes) with LDS fp32 accumulator.
// Edge-parallel: wave processes 4 edges per load round (16 lanes x ushort4),
// recs preloaded 64-wide + shfl broadcast; ds-atomic add into acc[dl][c].
// Epilogue: +bias (/relu), coalesced store. Row stride 65 spreads banks.
// ---------------------------------------------------------------------------
template<bool RELU, bool OUT_BF16>
__global__ __launch_bounds__(512) void k_agg(
    const ushort_t* __restrict__ H, const int2* __restrict__ recs,
    const int* __restrict__ base, const int* __restrict__ total,
    const float* __restrict__ bias, void* __restrict__ out, int N)
{
    __shared__ float acc[128 * 65];
    const int tid = threadIdx.x;
    const int k   = blockIdx.x;
    for (int i = tid; i < 128 * 65; i += 512) acc[i] = 0.f;
    __syncthreads();

    const int st  = base[k];
    const int end = st + total[k];
    const int wid  = tid >> 6;
    const int lane = tid & 63;
    const int q    = lane >> 4;
    const int c4   = (lane & 15) * 4;

    for (int j0 = st + wid * 64; j0 < end; j0 += 512) {
        int m = end - j0; if (m > 64) m = 64;
        int2 r = recs[j0 + (lane < m ? lane : m - 1)];
        float rw = __int_as_float(r.y);
        #pragma unroll 4
        for (int jj = 0; jj < m; jj += 4) {
            int idx = jj + q;
            int pk  = __shfl(r.x, idx);
            float w = __shfl(rw, idx);
            if (idx >= m) w = 0.f;                 // padded lanes add 0
            int s  = pk & 0x1FFFF;
            int dl = ((uint_t)pk) >> 17;
            ushort4 hv = *(const ushort4*)(H + (size_t)s * 64 + c4);
            float* a = acc + dl * 65 + c4;
            atomicAdd(a + 0, w * bf2f(hv.x));
            atomicAdd(a + 1, w * bf2f(hv.y));
            atomicAdd(a + 2, w * bf2f(hv.z));
            atomicAdd(a + 3, w * bf2f(hv.w));
        }
    }
    __syncthreads();

    const int n0 = k * 128;
    for (int i = tid * 4; i < 128 * 64; i += 512 * 4) {
        int n = i >> 6, c = i & 63;
        int ng = n0 + n;
        if (ng < N) {
            float4 bv = *(const float4*)(bias + c);
            const float* a = acc + n * 65 + c;
            float v0 = a[0] + bv.x, v1 = a[1] + bv.y;
            float v2 = a[2] + bv.z, v3 = a[3] + bv.w;
            if (RELU) {
                v0 = fmaxf(v0, 0.f); v1 = fmaxf(v1, 0.f);
                v2 = fmaxf(v2, 0.f); v3 = fmaxf(v3, 0.f);
            }
            if (OUT_BF16) {
                ushort4 pk = make_ushort4(f2bf(v0), f2bf(v1), f2bf(v2), f2bf(v3));
                *(ushort4*)((ushort_t*)out + (size_t)ng * 64 + c) = pk;
            } else {
                *(float4*)((float*)out + (size_t)ng * 64 + c) =
                    make_float4(v0, v1, v2, v3);
            }
        }
    }
}

// ---------------------------------------------------------------------------
extern "C" void kernel_launch(void* const* d_in, const int* in_sizes, int n_in,
                              void* d_out, int out_size, void* d_ws, size_t ws_size,
                              hipStream_t stream) {
    const float* x   = (const float*)d_in[0];
    const int*   ei  = (const int*)  d_in[1];
    const float* ew  = (const float*)d_in[2];
    const float* w1  = (const float*)d_in[3];
    const float* b1  = (const float*)d_in[4];
    const float* w2  = (const float*)d_in[5];
    const float* b2  = (const float*)d_in[6];
    float* out = (float*)d_out;

    const int N = N_NODES, E = N_EDGES;
    const int* src = ei;
    const int* dst = ei + E;

    char* p = (char*)d_ws;
    ushort_t* bufA   = (ushort_t*)p;  p += (size_t)N_NODES * 64 * 2;          // h1 / h2
    ushort_t* bufB   = (ushort_t*)p;  p += (size_t)N_NODES * 64 * 2;          // h1'
    int*      counts = (int*)p;       p += (size_t)NBLK_E * NBUCK * 4;
    int*      offs   = (int*)p;       p += (size_t)NBLK_E * NBUCK * 4;
    int*      total  = (int*)p;       p += 3136;
    int*      base   = (int*)p;       p += 3136;
    int2*     recs   = (int2*)p;      p += (size_t)E * 8;

    // ---- bucket sort (all coalesced / contention-free)
    k_count  <<<NBLK_E, 256,  0, stream>>>(dst, counts, E);
    k_colscan<<<NBUCK,  1024, 0, stream>>>(counts, offs, total);
    k_totscan<<<1,      1024, 0, stream>>>(total, base);
    k_placeB <<<NBLK_E, 1024, 0, stream>>>(src, dst, ew, offs, base, recs, E);

    // ---- layer 1
    k_gemm1<<<(N + 63) / 64, 256, 0, stream>>>(x, w1, bufA, N);
    k_agg<true, true><<<NBUCK, 512, 0, stream>>>(bufA, recs, base, total, b1, bufB, N);

    // ---- layer 2
    k_gemm2<<<(N + 63) / 64, 256, 0, stream>>>(bufB, w2, bufA, N);
    k_agg<false, false><<<NBUCK, 512, 0, stream>>>(bufA, recs, base, total, b2, out, N);
}

// Round 5
// 325.552 us; speedup vs baseline: 4.8754x; 4.8754x over previous
//
#include <hip/hip_runtime.h>
#include <hip/hip_bf16.h>

// GCN 2-layer: h1' = relu(S·(x@w1) + b1); out = S·(h1'@w2) + b2
// Two-level coalesced counting sort -> exact CSR by dst, then wave-per-node
// register-accumulating gather (4 edges per load instr, shfl-broadcast recs).
// Intermediates bf16. N=100000, E=1600000, IN=128, HID=64, OUT=64.
//
// Perf journal:
//  R1 scatter+atomics: 2862us (atomic-RMW bound, WRITE 1.6GB)
//  R2 CSR+wave-gather: 633us; R3 +4-edge gather, 64x64 gemm: 466us (k_place
//     122us: random 8B writes over 12.8MB -> 8x XCD write amp = 100MB HBM)
//  R4 bucket-LDS-agg: 1587us REGRESSION (6K waves, latency-starved gather).
//     -> keep R3 gather; fix placement with 2-level sort (this round).

#define N_NODES 100000
#define N_EDGES 1600000
#define NB1     98      // coarse buckets of 1024 dst nodes
#define T1      4096    // pass-1 tile (edges per block)
#define NT1     391     // ceil(E/T1)

typedef unsigned short ushort_t;
typedef unsigned int uint_t;

static __device__ __forceinline__ float bf2f(ushort_t h) {
    return __uint_as_float(((uint_t)h) << 16);
}
static __device__ __forceinline__ ushort_t f2bf(float f) {
    uint_t u = __float_as_uint(f);
    u = (u + 0x7FFF + ((u >> 16) & 1)) >> 16;   // RNE
    return (ushort_t)u;
}

// ---------------------------------------------------------------------------
// Sort stage 1: per-tile coarse-bucket histogram.
// ---------------------------------------------------------------------------
__global__ __launch_bounds__(512) void k_count1(
    const int* __restrict__ dst, int* __restrict__ counts, int E)
{
    __shared__ int cnt[NB1];
    const int t = threadIdx.x;
    if (t < NB1) cnt[t] = 0;
    __syncthreads();
    const int e0 = blockIdx.x * T1;
    const int e1 = min(E, e0 + T1);
    for (int e = e0 + t; e < e1; e += 512)
        atomicAdd(&cnt[dst[e] >> 10], 1);
    __syncthreads();
    if (t < NB1) counts[(size_t)blockIdx.x * NB1 + t] = cnt[t];
}

// Stage 2: per-bucket exclusive scan over tiles. offs[tile][k], ctot[k].
__global__ __launch_bounds__(512) void k_cscan(
    const int* __restrict__ counts, int* __restrict__ offs,
    int* __restrict__ ctot)
{
    __shared__ int s[512];
    const int t = threadIdx.x, k = blockIdx.x;
    const int v = (t < NT1) ? counts[(size_t)t * NB1 + k] : 0;
    s[t] = v;
    #pragma unroll
    for (int off = 1; off < 512; off <<= 1) {
        __syncthreads();
        int a = (t >= off) ? s[t - off] : 0;
        __syncthreads();
        s[t] += a;
    }
    __syncthreads();
    if (t < NT1) offs[(size_t)t * NB1 + k] = s[t] - v;
    if (t == 511) ctot[k] = s[511];
}

// Stage 3: exclusive scan of bucket totals -> bucket bases.
__global__ __launch_bounds__(128) void k_tscan(
    const int* __restrict__ ctot, int* __restrict__ cbase)
{
    __shared__ int s[128];
    const int t = threadIdx.x;
    const int v = (t < NB1) ? ctot[t] : 0;
    s[t] = v;
    #pragma unroll
    for (int off = 1; off < 128; off <<= 1) {
        __syncthreads();
        int a = (t >= off) ? s[t - off] : 0;
        __syncthreads();
        s[t] += a;
    }
    __syncthreads();
    if (t < NB1) cbase[t] = s[t] - v;
}

// ---------------------------------------------------------------------------
// Stage 4 (pass 1): LDS multisplit into 98 coarse buckets; write bucket-
// grouped runs (~41 recs = 330B contiguous). rec.x = (dst&1023)<<17 | src.
// ---------------------------------------------------------------------------
__global__ __launch_bounds__(512) void k_pass1(
    const int* __restrict__ src, const int* __restrict__ dst,
    const float* __restrict__ ew, const int* __restrict__ offs,
    const int* __restrict__ cbase, int2* __restrict__ recs1, int E)
{
    __shared__ int cnt[NB1], start[NB1], cursor[NB1], gb[NB1];
    __shared__ int s[128];
    __shared__ int2 stg[T1];            // 32 KB
    __shared__ unsigned char sb[T1];    // 4 KB
    const int t = threadIdx.x, b = blockIdx.x;

    if (t < NB1) cnt[t] = 0;
    __syncthreads();
    const int e0 = b * T1;
    const int e1 = min(E, e0 + T1);
    for (int e = e0 + t; e < e1; e += 512)
        atomicAdd(&cnt[dst[e] >> 10], 1);
    __syncthreads();
    int v = 0;
    if (t < 128) { v = (t < NB1) ? cnt[t] : 0; s[t] = v; }
    #pragma unroll
    for (int off = 1; off < 128; off <<= 1) {
        __syncthreads();
        int a = (t < 128 && t >= off) ? s[t - off] : 0;
        __syncthreads();
        if (t < 128) s[t] += a;
    }
    __syncthreads();
    if (t < NB1) {
        int st = s[t] - v;
        start[t]  = st;
        cursor[t] = st;
        gb[t]     = cbase[t] + offs[(size_t)b * NB1 + t];
    }
    __syncthreads();
    for (int e = e0 + t; e < e1; e += 512) {
        int d  = dst[e];
        int bk = d >> 10;
        int p  = atomicAdd(&cursor[bk], 1);
        int2 r;
        r.x = ((d & 1023) << 17) | src[e];
        r.y = __float_as_int(ew[e]);
        stg[p] = r;
        sb[p]  = (unsigned char)bk;
    }
    __syncthreads();
    const int n = e1 - e0;
    for (int i = t; i < n; i += 512) {
        int bk = sb[i];
        recs1[gb[bk] + (i - start[bk])] = stg[i];
    }
}

// ---------------------------------------------------------------------------
// Pass 2: one block per coarse bucket -> exact per-node CSR within the
// bucket's exclusive window (scattered writes stay in one XCD's L2).
// Emits node_start / node_cnt. recs2.x = src, recs2.y = fp32 weight.
// ---------------------------------------------------------------------------
__global__ __launch_bounds__(1024) void k_pass2(
    const int2* __restrict__ recs1, const int* __restrict__ cbase,
    const int* __restrict__ ctot, int2* __restrict__ recs2,
    int* __restrict__ node_start, int* __restrict__ node_cnt, int N)
{
    __shared__ int cnt[1024];
    __shared__ int s[1024];
    __shared__ int cursor[1024];
    const int t = threadIdx.x, b = blockIdx.x;
    const int lo = cbase[b];
    const int hi = lo + ctot[b];

    cnt[t] = 0;
    __syncthreads();
    for (int j = lo + t; j < hi; j += 1024)
        atomicAdd(&cnt[((uint_t)recs1[j].x) >> 17], 1);
    __syncthreads();
    const int v = cnt[t];
    s[t] = v;
    #pragma unroll
    for (int off = 1; off < 1024; off <<= 1) {
        __syncthreads();
        int a = (t >= off) ? s[t - off] : 0;
        __syncthreads();
        s[t] += a;
    }
    __syncthreads();
    const int stl = s[t] - v;            // local exclusive offset
    cursor[t] = stl;
    const int ng = b * 1024 + t;
    if (ng < N) {
        node_start[ng] = lo + stl;
        node_cnt[ng]   = v;
    }
    __syncthreads();
    for (int j = lo + t; j < hi; j += 1024) {
        int2 r = recs1[j];
        int dl = ((uint_t)r.x) >> 17;
        int p  = atomicAdd(&cursor[dl], 1);
        int2 o;
        o.x = r.x & 0x1FFFF;
        o.y = r.y;
        recs2[lo + p] = o;
    }
}

// ---------------------------------------------------------------------------
// GEMM1: Y[bf16, N x 64] = X[f32, N x 128] @ W[128 x 64]
// ---------------------------------------------------------------------------
__global__ __launch_bounds__(256) void k_gemm1(
    const float* __restrict__ X, const float* __restrict__ W,
    ushort_t* __restrict__ Y, int N)
{
    const int K = 128;
    __shared__ float sW[K * 64];
    __shared__ float sX[64 * (K + 4)];
    const int tid  = threadIdx.x;
    const int row0 = blockIdx.x * 64;

    #pragma unroll
    for (int i = tid * 4; i < K * 64; i += 256 * 4)
        *(float4*)(sW + i) = *(const float4*)(W + i);
    #pragma unroll
    for (int i = tid; i < 64 * (K / 4); i += 256) {
        int r  = i >> 5;
        int c4 = (i & 31) * 4;
        int rg = row0 + r; if (rg > N - 1) rg = N - 1;
        *(float4*)(sX + r * (K + 4) + c4) =
            *(const float4*)(X + (size_t)rg * K + c4);
    }
    __syncthreads();

    const int c0 = (tid & 15) * 4;
    const int r0 = (tid >> 4) * 4;
    float acc[4][4];
    #pragma unroll
    for (int i = 0; i < 4; ++i)
        #pragma unroll
        for (int j = 0; j < 4; ++j) acc[i][j] = 0.f;

    for (int k4 = 0; k4 < K; k4 += 4) {
        float4 xv[4];
        #pragma unroll
        for (int i = 0; i < 4; ++i)
            xv[i] = *(const float4*)(sX + (r0 + i) * (K + 4) + k4);
        #pragma unroll
        for (int kk = 0; kk < 4; ++kk) {
            float4 wv = *(const float4*)(sW + (k4 + kk) * 64 + c0);
            #pragma unroll
            for (int i = 0; i < 4; ++i) {
                float xs = (kk == 0) ? xv[i].x : (kk == 1) ? xv[i].y
                         : (kk == 2) ? xv[i].z : xv[i].w;
                acc[i][0] = fmaf(xs, wv.x, acc[i][0]);
                acc[i][1] = fmaf(xs, wv.y, acc[i][1]);
                acc[i][2] = fmaf(xs, wv.z, acc[i][2]);
                acc[i][3] = fmaf(xs, wv.w, acc[i][3]);
            }
        }
    }
    #pragma unroll
    for (int i = 0; i < 4; ++i) {
        int rg = row0 + r0 + i;
        if (rg < N) {
            ushort4 pk = make_ushort4(f2bf(acc[i][0]), f2bf(acc[i][1]),
                                      f2bf(acc[i][2]), f2bf(acc[i][3]));
            *(ushort4*)(Y + (size_t)rg * 64 + c0) = pk;
        }
    }
}

// ---------------------------------------------------------------------------
// GEMM2: Y[bf16, N x 64] = X[bf16, N x 64] @ W[64 x 64]
// ---------------------------------------------------------------------------
__global__ __launch_bounds__(256) void k_gemm2(
    const ushort_t* __restrict__ X, const float* __restrict__ W,
    ushort_t* __restrict__ Y, int N)
{
    const int K = 64;
    __shared__ float sW[K * 64];
    __shared__ float sX[64 * (K + 4)];
    const int tid  = threadIdx.x;
    const int row0 = blockIdx.x * 64;

    #pragma unroll
    for (int i = tid * 4; i < K * 64; i += 256 * 4)
        *(float4*)(sW + i) = *(const float4*)(W + i);
    #pragma unroll
    for (int i = tid; i < 64 * (K / 4); i += 256) {
        int r  = i >> 4;
        int c4 = (i & 15) * 4;
        int rg = row0 + r; if (rg > N - 1) rg = N - 1;
        ushort4 v = *(const ushort4*)(X + (size_t)rg * K + c4);
        float* o = sX + r * (K + 4) + c4;
        o[0] = bf2f(v.x); o[1] = bf2f(v.y); o[2] = bf2f(v.z); o[3] = bf2f(v.w);
    }
    __syncthreads();

    const int c0 = (tid & 15) * 4;
    const int r0 = (tid >> 4) * 4;
    float acc[4][4];
    #pragma unroll
    for (int i = 0; i < 4; ++i)
        #pragma unroll
        for (int j = 0; j < 4; ++j) acc[i][j] = 0.f;

    for (int k4 = 0; k4 < K; k4 += 4) {
        float4 xv[4];
        #pragma unroll
        for (int i = 0; i < 4; ++i)
            xv[i] = *(const float4*)(sX + (r0 + i) * (K + 4) + k4);
        #pragma unroll
        for (int kk = 0; kk < 4; ++kk) {
            float4 wv = *(const float4*)(sW + (k4 + kk) * 64 + c0);
            #pragma unroll
            for (int i = 0; i < 4; ++i) {
                float xs = (kk == 0) ? xv[i].x : (kk == 1) ? xv[i].y
                         : (kk == 2) ? xv[i].z : xv[i].w;
                acc[i][0] = fmaf(xs, wv.x, acc[i][0]);
                acc[i][1] = fmaf(xs, wv.y, acc[i][1]);
                acc[i][2] = fmaf(xs, wv.z, acc[i][2]);
                acc[i][3] = fmaf(xs, wv.w, acc[i][3]);
            }
        }
    }
    #pragma unroll
    for (int i = 0; i < 4; ++i) {
        int rg = row0 + r0 + i;
        if (rg < N) {
            ushort4 pk = make_ushort4(f2bf(acc[i][0]), f2bf(acc[i][1]),
                                      f2bf(acc[i][2]), f2bf(acc[i][3]));
            *(ushort4*)(Y + (size_t)rg * 64 + c0) = pk;
        }
    }
}

// ---------------------------------------------------------------------------
// Gather-reduce: one wave per node; quad q handles edge jj+q; 16 lanes x
// ushort4 per edge; recs preloaded 64-wide + shfl broadcast. No atomics.
// ---------------------------------------------------------------------------
template<bool RELU, bool OUT_BF16>
__global__ __launch_bounds__(256) void k_gather(
    const ushort_t* __restrict__ H, const int2* __restrict__ recs,
    const int* __restrict__ node_start, const int* __restrict__ node_cnt,
    const float* __restrict__ bias, void* __restrict__ out)
{
    const int wid  = threadIdx.x >> 6;
    const int lane = threadIdx.x & 63;
    const int n    = blockIdx.x * 4 + wid;   // grid = N/4 exactly

    const int start = node_start[n];
    const int end   = start + node_cnt[n];
    const int q     = lane >> 4;
    const int c4    = (lane & 15) * 4;

    float a0 = 0.f, a1 = 0.f, a2 = 0.f, a3 = 0.f;

    for (int base = start; base < end; base += 64) {
        const int m = (end - base < 64) ? (end - base) : 64;
        int2 r = recs[base + (lane < m ? lane : 0)];
        float rw = __int_as_float(r.y);
        #pragma unroll 4
        for (int jj = 0; jj < m; jj += 4) {
            int idx = jj + q;
            int s   = __shfl(r.x, idx);
            float w = __shfl(rw, idx);
            if (idx >= m) w = 0.f;
            ushort4 hv = *(const ushort4*)(H + (size_t)s * 64 + c4);
            a0 = fmaf(w, bf2f(hv.x), a0);
            a1 = fmaf(w, bf2f(hv.y), a1);
            a2 = fmaf(w, bf2f(hv.z), a2);
            a3 = fmaf(w, bf2f(hv.w), a3);
        }
    }
    a0 += __shfl_down(a0, 32); a1 += __shfl_down(a1, 32);
    a2 += __shfl_down(a2, 32); a3 += __shfl_down(a3, 32);
    a0 += __shfl_down(a0, 16); a1 += __shfl_down(a1, 16);
    a2 += __shfl_down(a2, 16); a3 += __shfl_down(a3, 16);

    if (lane < 16) {
        float4 bv = *(const float4*)(bias + c4);
        float v0 = a0 + bv.x, v1 = a1 + bv.y, v2 = a2 + bv.z, v3 = a3 + bv.w;
        if (RELU) {
            v0 = fmaxf(v0, 0.f); v1 = fmaxf(v1, 0.f);
            v2 = fmaxf(v2, 0.f); v3 = fmaxf(v3, 0.f);
        }
        if (OUT_BF16) {
            ushort4 pk = make_ushort4(f2bf(v0), f2bf(v1), f2bf(v2), f2bf(v3));
            *(ushort4*)((ushort_t*)out + (size_t)n * 64 + c4) = pk;
        } else {
            *(float4*)((float*)out + (size_t)n * 64 + c4) =
                make_float4(v0, v1, v2, v3);
        }
    }
}

// ---------------------------------------------------------------------------
extern "C" void kernel_launch(void* const* d_in, const int* in_sizes, int n_in,
                              void* d_out, int out_size, void* d_ws, size_t ws_size,
                              hipStream_t stream) {
    const float* x   = (const float*)d_in[0];
    const int*   ei  = (const int*)  d_in[1];
    const float* ew  = (const float*)d_in[2];
    const float* w1  = (const float*)d_in[3];
    const float* b1  = (const float*)d_in[4];
    const float* w2  = (const float*)d_in[5];
    const float* b2  = (const float*)d_in[6];
    float* out = (float*)d_out;

    const int N = N_NODES, E = N_EDGES;
    const int* src = ei;
    const int* dst = ei + E;

    char* p = (char*)d_ws;
    ushort_t* bufA   = (ushort_t*)p;  p += (size_t)N_NODES * 64 * 2;   // 12.8MB: h1 / h2
    int2*     recs2  = (int2*)p;      p += (size_t)N_EDGES * 8;        // 12.8MB: exact CSR
    // recs1 (pass-1 output) aliases bufB: dead before gather1 writes bufB.
    int2*     recs1  = (int2*)p;
    ushort_t* bufB   = (ushort_t*)p;  p += (size_t)N_EDGES * 8;        // 12.8MB
    int*      counts = (int*)p;       p += (size_t)NT1 * NB1 * 4;
    int*      offs   = (int*)p;       p += (size_t)NT1 * NB1 * 4;
    int*      ctot   = (int*)p;       p += 512;
    int*      cbase  = (int*)p;       p += 512;
    int*      nstart = (int*)p;       p += (size_t)N_NODES * 4;
    int*      ncnt   = (int*)p;       p += (size_t)N_NODES * 4;

    // ---- two-level sort to exact CSR (all writes coalesced or L2-confined)
    k_count1<<<NT1, 512, 0, stream>>>(dst, counts, E);
    k_cscan <<<NB1, 512, 0, stream>>>(counts, offs, ctot);
    k_tscan <<<1,   128, 0, stream>>>(ctot, cbase);
    k_pass1 <<<NT1, 512, 0, stream>>>(src, dst, ew, offs, cbase, recs1, E);
    k_pass2 <<<NB1, 1024, 0, stream>>>(recs1, cbase, ctot, recs2, nstart, ncnt, N);

    // ---- layer 1
    k_gemm1<<<(N + 63) / 64, 256, 0, stream>>>(x, w1, bufA, N);
    k_gather<true, true><<<N / 4, 256, 0, stream>>>(bufA, recs2, nstart, ncnt, b1, bufB);

    // ---- layer 2
    k_gemm2<<<(N + 63) / 64, 256, 0, stream>>>(bufB, w2, bufA, N);
    k_gather<false, false><<<N / 4, 256, 0, stream>>>(bufA, recs2, nstart, ncnt, b2, out);
}

// Round 6
// 262.114 us; speedup vs baseline: 6.0554x; 1.2420x over previous
//
#include <hip/hip_runtime.h>
#include <hip/hip_bf16.h>

// GCN 2-layer: h1' = relu(S·(x@w1) + b1); out = S·(h1'@w2) + b2
// Two-level coalesced counting sort -> exact CSR by dst; wave-per-node
// register-accumulating gather (8 edges per 16B-load round); bf16 MFMA GEMMs.
// N=100000, E=1600000, IN=128, HID=64, OUT=64.
//
// Perf journal:
//  R1 scatter+atomics: 2862us (atomic-RMW bound, WRITE 1.6GB)
//  R2 CSR+wave-gather: 633us; R3 +4-edge gather, 64x64 gemm: 466us
//  R4 bucket-LDS-agg: 1587us REGRESSION (6K waves, latency-starved)
//  R5 two-level sort: 326us (k_gemm2 54us VGPR=232 occ 8.6%! gather 53us)
//  R6 (this): MFMA bf16 gemms, ushort8 gather, 196-bucket sort.

#define N_NODES 100000
#define N_EDGES 1600000
#define NB1     196     // coarse buckets of 512 dst nodes
#define T1      4096    // pass-1 tile (edges per block)
#define NT1     391     // ceil(E/T1)

typedef unsigned short ushort_t;
typedef unsigned int uint_t;
typedef __attribute__((ext_vector_type(8))) short bf16x8;
typedef __attribute__((ext_vector_type(4))) float floatx4;
typedef __attribute__((ext_vector_type(8))) ushort_t ushort8v;

static __device__ __forceinline__ float bf2f(ushort_t h) {
    return __uint_as_float(((uint_t)h) << 16);
}
static __device__ __forceinline__ ushort_t f2bf(float f) {
    uint_t u = __float_as_uint(f);
    u = (u + 0x7FFF + ((u >> 16) & 1)) >> 16;   // RNE
    return (ushort_t)u;
}

// ---------------------------------------------------------------------------
// Sort stage 1: per-tile coarse-bucket histogram.
// ---------------------------------------------------------------------------
__global__ __launch_bounds__(512) void k_count1(
    const int* __restrict__ dst, int* __restrict__ counts, int E)
{
    __shared__ int cnt[NB1];
    const int t = threadIdx.x;
    if (t < NB1) cnt[t] = 0;
    __syncthreads();
    const int e0 = blockIdx.x * T1;
    const int e1 = min(E, e0 + T1);
    for (int e = e0 + t; e < e1; e += 512)
        atomicAdd(&cnt[dst[e] >> 9], 1);
    __syncthreads();
    if (t < NB1) counts[(size_t)blockIdx.x * NB1 + t] = cnt[t];
}

// Stage 2: per-bucket exclusive scan over tiles. offs[tile][k], ctot[k].
__global__ __launch_bounds__(512) void k_cscan(
    const int* __restrict__ counts, int* __restrict__ offs,
    int* __restrict__ ctot)
{
    __shared__ int s[512];
    const int t = threadIdx.x, k = blockIdx.x;
    const int v = (t < NT1) ? counts[(size_t)t * NB1 + k] : 0;
    s[t] = v;
    #pragma unroll
    for (int off = 1; off < 512; off <<= 1) {
        __syncthreads();
        int a = (t >= off) ? s[t - off] : 0;
        __syncthreads();
        s[t] += a;
    }
    __syncthreads();
    if (t < NT1) offs[(size_t)t * NB1 + k] = s[t] - v;
    if (t == 511) ctot[k] = s[511];
}

// Stage 3: exclusive scan of bucket totals -> bucket bases.
__global__ __launch_bounds__(256) void k_tscan(
    const int* __restrict__ ctot, int* __restrict__ cbase)
{
    __shared__ int s[256];
    const int t = threadIdx.x;
    const int v = (t < NB1) ? ctot[t] : 0;
    s[t] = v;
    #pragma unroll
    for (int off = 1; off < 256; off <<= 1) {
        __syncthreads();
        int a = (t >= off) ? s[t - off] : 0;
        __syncthreads();
        s[t] += a;
    }
    __syncthreads();
    if (t < NB1) cbase[t] = s[t] - v;
}

// ---------------------------------------------------------------------------
// Stage 4 (pass 1): LDS multisplit into 196 coarse buckets; write bucket-
// grouped runs (~21 recs = 167B). rec.x = (dst&511)<<17 | src (src<2^17).
// ---------------------------------------------------------------------------
__global__ __launch_bounds__(512) void k_pass1(
    const int* __restrict__ src, const int* __restrict__ dst,
    const float* __restrict__ ew, const int* __restrict__ offs,
    const int* __restrict__ cbase, int2* __restrict__ recs1, int E)
{
    __shared__ int cnt[NB1], start[NB1], cursor[NB1], gb[NB1];
    __shared__ int s[256];
    __shared__ int2 stg[T1];            // 32 KB
    __shared__ unsigned char sb[T1];    // 4 KB
    const int t = threadIdx.x, b = blockIdx.x;

    if (t < NB1) cnt[t] = 0;
    __syncthreads();
    const int e0 = b * T1;
    const int e1 = min(E, e0 + T1);
    for (int e = e0 + t; e < e1; e += 512)
        atomicAdd(&cnt[dst[e] >> 9], 1);
    __syncthreads();
    int v = 0;
    if (t < 256) { v = (t < NB1) ? cnt[t] : 0; s[t] = v; }
    #pragma unroll
    for (int off = 1; off < 256; off <<= 1) {
        __syncthreads();
        int a = (t < 256 && t >= off) ? s[t - off] : 0;
        __syncthreads();
        if (t < 256) s[t] += a;
    }
    __syncthreads();
    if (t < NB1) {
        int st = s[t] - v;
        start[t]  = st;
        cursor[t] = st;
        gb[t]     = cbase[t] + offs[(size_t)b * NB1 + t];
    }
    __syncthreads();
    for (int e = e0 + t; e < e1; e += 512) {
        int d  = dst[e];
        int bk = d >> 9;
        int p  = atomicAdd(&cursor[bk], 1);
        int2 r;
        r.x = ((d & 511) << 17) | src[e];
        r.y = __float_as_int(ew[e]);
        stg[p] = r;
        sb[p]  = (unsigned char)bk;
    }
    __syncthreads();
    const int n = e1 - e0;
    for (int i = t; i < n; i += 512) {
        int bk = sb[i];
        recs1[gb[bk] + (i - start[bk])] = stg[i];
    }
}

// ---------------------------------------------------------------------------
// Pass 2: one block per coarse bucket (512 nodes) -> exact per-node CSR in
// the bucket's exclusive window. Emits node_start / node_cnt.
// ---------------------------------------------------------------------------
__global__ __launch_bounds__(512) void k_pass2(
    const int2* __restrict__ recs1, const int* __restrict__ cbase,
    const int* __restrict__ ctot, int2* __restrict__ recs2,
    int* __restrict__ node_start, int* __restrict__ node_cnt, int N)
{
    __shared__ int cnt[512];
    __shared__ int s[512];
    __shared__ int cursor[512];
    const int t = threadIdx.x, b = blockIdx.x;
    const int lo = cbase[b];
    const int hi = lo + ctot[b];

    cnt[t] = 0;
    __syncthreads();
    for (int j = lo + t; j < hi; j += 512)
        atomicAdd(&cnt[((uint_t)recs1[j].x) >> 17], 1);
    __syncthreads();
    const int v = cnt[t];
    s[t] = v;
    #pragma unroll
    for (int off = 1; off < 512; off <<= 1) {
        __syncthreads();
        int a = (t >= off) ? s[t - off] : 0;
        __syncthreads();
        s[t] += a;
    }
    __syncthreads();
    const int stl = s[t] - v;
    cursor[t] = stl;
    const int ng = b * 512 + t;
    if (ng < N) {
        node_start[ng] = lo + stl;
        node_cnt[ng]   = v;
    }
    __syncthreads();
    for (int j = lo + t; j < hi; j += 512) {
        int2 r = recs1[j];
        int dl = ((uint_t)r.x) >> 17;
        int p  = atomicAdd(&cursor[dl], 1);
        int2 o;
        o.x = r.x & 0x1FFFF;
        o.y = r.y;
        recs2[lo + p] = o;
    }
}

// ---------------------------------------------------------------------------
// MFMA GEMM1: Y[bf16, N x 64] = bf16(X[f32, N x 128]) @ bf16(W[128 x 64])
// Block: 64 rows, 4 waves; wave w does rows w*16..w*16+15 over 4 n-tiles.
// LDS rows padded to 136 bf16 (272B): ds_read_b128 -> uniform 8/bank.
// A-frag: A[m=lane&15][k=quad*8+j]; B-frag: B[k=quad*8+j][n=lane&15];
// C/D: row=quad*4+reg, col=lane&15 (m89/m120-verified layouts).
// ---------------------------------------------------------------------------
__global__ __launch_bounds__(256) void k_gemm1(
    const float* __restrict__ X, const float* __restrict__ W,
    ushort_t* __restrict__ Y, int N)
{
    __shared__ ushort_t sA[64 * 136];   // 17408 B
    __shared__ ushort_t sB[64 * 136];   // B^T: sB[n*136 + k]
    const int tid  = threadIdx.x;
    const int row0 = blockIdx.x * 64;

    for (int i = tid; i < 64 * 32; i += 256) {         // A: 64 rows x 32 f4
        int r = i >> 5, c4 = (i & 31) * 4;
        int rg = row0 + r; if (rg > N - 1) rg = N - 1;
        float4 v = *(const float4*)(X + (size_t)rg * 128 + c4);
        ushort4 pk = make_ushort4(f2bf(v.x), f2bf(v.y), f2bf(v.z), f2bf(v.w));
        *(ushort4*)(sA + r * 136 + c4) = pk;
    }
    for (int i = tid; i < 128 * 16; i += 256) {        // B: 128 rows x 16 f4
        int k = i >> 4, n4 = (i & 15) * 4;
        float4 v = *(const float4*)(W + (size_t)k * 64 + n4);
        sB[(n4 + 0) * 136 + k] = f2bf(v.x);
        sB[(n4 + 1) * 136 + k] = f2bf(v.y);
        sB[(n4 + 2) * 136 + k] = f2bf(v.z);
        sB[(n4 + 3) * 136 + k] = f2bf(v.w);
    }
    __syncthreads();

    const int wid = tid >> 6, lane = tid & 63;
    const int m = lane & 15, quad = lane >> 4;
    floatx4 acc[4] = {};

    #pragma unroll
    for (int ks = 0; ks < 4; ++ks) {
        bf16x8 a = *(const bf16x8*)(sA + (wid * 16 + m) * 136 + ks * 32 + quad * 8);
        #pragma unroll
        for (int nt = 0; nt < 4; ++nt) {
            bf16x8 bfr = *(const bf16x8*)(sB + (nt * 16 + m) * 136 + ks * 32 + quad * 8);
            acc[nt] = __builtin_amdgcn_mfma_f32_16x16x32_bf16(a, bfr, acc[nt], 0, 0, 0);
        }
    }
    #pragma unroll
    for (int nt = 0; nt < 4; ++nt)
        #pragma unroll
        for (int r = 0; r < 4; ++r) {
            int grow = row0 + wid * 16 + quad * 4 + r;
            if (grow < N)
                Y[(size_t)grow * 64 + nt * 16 + m] = f2bf(acc[nt][r]);
        }
}

// ---------------------------------------------------------------------------
// MFMA GEMM2: Y[bf16, N x 64] = X[bf16, N x 64] @ bf16(W[64 x 64])
// ---------------------------------------------------------------------------
__global__ __launch_bounds__(256) void k_gemm2(
    const ushort_t* __restrict__ X, const float* __restrict__ W,
    ushort_t* __restrict__ Y, int N)
{
    __shared__ ushort_t sA[64 * 72];    // 9216 B (144B rows: 16B-aligned)
    __shared__ ushort_t sB[64 * 72];
    const int tid  = threadIdx.x;
    const int row0 = blockIdx.x * 64;

    for (int i = tid; i < 64 * 16; i += 256) {         // A: 64 rows x 16 us4
        int r = i >> 4, c4 = (i & 15) * 4;
        int rg = row0 + r; if (rg > N - 1) rg = N - 1;
        *(ushort4*)(sA + r * 72 + c4) =
            *(const ushort4*)(X + (size_t)rg * 64 + c4);
    }
    for (int i = tid; i < 64 * 16; i += 256) {         // B: 64 rows x 16 f4
        int k = i >> 4, n4 = (i & 15) * 4;
        float4 v = *(const float4*)(W + (size_t)k * 64 + n4);
        sB[(n4 + 0) * 72 + k] = f2bf(v.x);
        sB[(n4 + 1) * 72 + k] = f2bf(v.y);
        sB[(n4 + 2) * 72 + k] = f2bf(v.z);
        sB[(n4 + 3) * 72 + k] = f2bf(v.w);
    }
    __syncthreads();

    const int wid = tid >> 6, lane = tid & 63;
    const int m = lane & 15, quad = lane >> 4;
    floatx4 acc[4] = {};

    #pragma unroll
    for (int ks = 0; ks < 2; ++ks) {
        bf16x8 a = *(const bf16x8*)(sA + (wid * 16 + m) * 72 + ks * 32 + quad * 8);
        #pragma unroll
        for (int nt = 0; nt < 4; ++nt) {
            bf16x8 bfr = *(const bf16x8*)(sB + (nt * 16 + m) * 72 + ks * 32 + quad * 8);
            acc[nt] = __builtin_amdgcn_mfma_f32_16x16x32_bf16(a, bfr, acc[nt], 0, 0, 0);
        }
    }
    #pragma unroll
    for (int nt = 0; nt < 4; ++nt)
        #pragma unroll
        for (int r = 0; r < 4; ++r) {
            int grow = row0 + wid * 16 + quad * 4 + r;
            if (grow < N)
                Y[(size_t)grow * 64 + nt * 16 + m] = f2bf(acc[nt][r]);
        }
}

// ---------------------------------------------------------------------------
// Gather-reduce: one wave per node; oct o = lane>>3 handles edge jj+o;
// 8 lanes x ushort8 (16B) per edge -> 8 edges per load instruction.
// recs preloaded 64-wide + shfl broadcast. No atomics.
// ---------------------------------------------------------------------------
template<bool RELU, bool OUT_BF16>
__global__ __launch_bounds__(256) void k_gather(
    const ushort_t* __restrict__ H, const int2* __restrict__ recs,
    const int* __restrict__ node_start, const int* __restrict__ node_cnt,
    const float* __restrict__ bias, void* __restrict__ out)
{
    const int wid  = threadIdx.x >> 6;
    const int lane = threadIdx.x & 63;
    const int n    = blockIdx.x * 4 + wid;   // grid = N/4 exactly

    const int start = node_start[n];
    const int end   = start + node_cnt[n];
    const int oct   = lane >> 3;
    const int c8    = (lane & 7) * 8;

    float a[8];
    #pragma unroll
    for (int i = 0; i < 8; ++i) a[i] = 0.f;

    for (int base = start; base < end; base += 64) {
        const int m = (end - base < 64) ? (end - base) : 64;
        int2 r = recs[base + (lane < m ? lane : 0)];
        float rw = __int_as_float(r.y);
        #pragma unroll 8
        for (int jj = 0; jj < m; jj += 8) {
            int idx = jj + oct;
            int s   = __shfl(r.x, idx);
            float w = __shfl(rw, idx);
            if (idx >= m) w = 0.f;
            ushort8v hv = *(const ushort8v*)(H + (size_t)s * 64 + c8);
            #pragma unroll
            for (int i = 0; i < 8; ++i)
                a[i] = fmaf(w, bf2f(hv[i]), a[i]);
        }
    }
    #pragma unroll
    for (int i = 0; i < 8; ++i) {
        a[i] += __shfl_down(a[i], 32);
        a[i] += __shfl_down(a[i], 16);
        a[i] += __shfl_down(a[i], 8);
    }

    if (lane < 8) {
        float4 b0 = *(const float4*)(bias + c8);
        float4 b1v = *(const float4*)(bias + c8 + 4);
        float v[8];
        v[0] = a[0] + b0.x;  v[1] = a[1] + b0.y;
        v[2] = a[2] + b0.z;  v[3] = a[3] + b0.w;
        v[4] = a[4] + b1v.x; v[5] = a[5] + b1v.y;
        v[6] = a[6] + b1v.z; v[7] = a[7] + b1v.w;
        if (RELU) {
            #pragma unroll
            for (int i = 0; i < 8; ++i) v[i] = fmaxf(v[i], 0.f);
        }
        if (OUT_BF16) {
            ushort8v pk;
            #pragma unroll
            for (int i = 0; i < 8; ++i) pk[i] = f2bf(v[i]);
            *(ushort8v*)((ushort_t*)out + (size_t)n * 64 + c8) = pk;
        } else {
            *(float4*)((float*)out + (size_t)n * 64 + c8) =
                make_float4(v[0], v[1], v[2], v[3]);
            *(float4*)((float*)out + (size_t)n * 64 + c8 + 4) =
                make_float4(v[4], v[5], v[6], v[7]);
        }
    }
}

// ---------------------------------------------------------------------------
extern "C" void kernel_launch(void* const* d_in, const int* in_sizes, int n_in,
                              void* d_out, int out_size, void* d_ws, size_t ws_size,
                              hipStream_t stream) {
    const float* x   = (const float*)d_in[0];
    const int*   ei  = (const int*)  d_in[1];
    const float* ew  = (const float*)d_in[2];
    const float* w1  = (const float*)d_in[3];
    const float* b1  = (const float*)d_in[4];
    const float* w2  = (const float*)d_in[5];
    const float* b2  = (const float*)d_in[6];
    float* out = (float*)d_out;

    const int N = N_NODES, E = N_EDGES;
    const int* src = ei;
    const int* dst = ei + E;

    char* p = (char*)d_ws;
    ushort_t* bufA   = (ushort_t*)p;  p += (size_t)N_NODES * 64 * 2;   // 12.8MB: h1 / h2
    int2*     recs2  = (int2*)p;      p += (size_t)N_EDGES * 8;        // 12.8MB: exact CSR
    // recs1 (pass-1 output) aliases bufB: dead before gather1 writes bufB.
    int2*     recs1  = (int2*)p;
    ushort_t* bufB   = (ushort_t*)p;  p += (size_t)N_EDGES * 8;        // 12.8MB
    int*      counts = (int*)p;       p += (size_t)NT1 * NB1 * 4;
    int*      offs   = (int*)p;       p += (size_t)NT1 * NB1 * 4;
    int*      ctot   = (int*)p;       p += 1024;
    int*      cbase  = (int*)p;       p += 1024;
    int*      nstart = (int*)p;       p += (size_t)N_NODES * 4;
    int*      ncnt   = (int*)p;       p += (size_t)N_NODES * 4;

    // ---- two-level sort to exact CSR
    k_count1<<<NT1, 512, 0, stream>>>(dst, counts, E);
    k_cscan <<<NB1, 512, 0, stream>>>(counts, offs, ctot);
    k_tscan <<<1,   256, 0, stream>>>(ctot, cbase);
    k_pass1 <<<NT1, 512, 0, stream>>>(src, dst, ew, offs, cbase, recs1, E);
    k_pass2 <<<NB1, 512, 0, stream>>>(recs1, cbase, ctot, recs2, nstart, ncnt, N);

    // ---- layer 1
    k_gemm1<<<(N + 63) / 64, 256, 0, stream>>>(x, w1, bufA, N);
    k_gather<true, true><<<N / 4, 256, 0, stream>>>(bufA, recs2, nstart, ncnt, b1, bufB);

    // ---- layer 2
    k_gemm2<<<(N + 63) / 64, 256, 0, stream>>>(bufB, w2, bufA, N);
    k_gather<false, false><<<N / 4, 256, 0, stream>>>(bufA, recs2, nstart, ncnt, b2, out);
}